// Round 1
// baseline (1093.807 us; speedup 1.0000x reference)
//
#include <hip/hip_runtime.h>

// ---------------------------------------------------------------------------
// MemoryOptimizedMLA on gfx950 — absorbed-MLA formulation.
//
//   c_kv = h@W_dkv+b ; c_q = h@W_dq+b ; k_rot = rope(h@W_kr+b)
//   W_qk[h] = W_uq_h @ W_uk_h^T (128x128), b_qabs[h] = b_uq_h @ W_uk_h^T
//   q_abs = c_q@W_qk + b_qabs ; q_rot = rope(c_q@W_qr + b_qr)
//   scores = (q_abs . c_kv + q_rot . k_rot)/sqrt(640)   (b_uk is softmax-inv.)
//   ctx = softmax(scores) @ c_kv      (128 dims, flash/online-softmax)
//   out = ctx @ W_combT^T + (b_uv@W_o + b_o),  W_comb[h] = W_uv_h @ W_o_h
// ---------------------------------------------------------------------------

typedef unsigned short ushort_t;
typedef __attribute__((ext_vector_type(8)))  short          short8;
typedef __attribute__((ext_vector_type(8)))  unsigned short us8;
typedef __attribute__((ext_vector_type(4)))  float          f32x4;

#define SCALE_ATT 0.0395284707521047f  /* 1/sqrt(640) */

static __device__ inline unsigned short f2bf(float f) {
  union { float f; unsigned u; } v; v.f = f;
  unsigned r = (v.u + 0x7fffu + ((v.u >> 16) & 1u)) >> 16;
  return (unsigned short)r;
}
static __device__ inline float bf2f(unsigned short u) {
  union { unsigned u; float f; } v; v.u = ((unsigned)u) << 16;
  return v.f;
}
static __device__ inline f32x4 MFMA(short8 a, short8 b, f32x4 c) {
  return __builtin_amdgcn_mfma_f32_16x16x32_bf16(a, b, c, 0, 0, 0);
}

// ---------------------------------------------------------------------------
// bvec[n] = sum_k b_uv[k]*W_o[k][n] + b_o[n]      grid 160, block 256 (8k x 32n)
__global__ __launch_bounds__(256) void k_bvec(const float* __restrict__ buv,
                                              const float* __restrict__ Wo,
                                              const float* __restrict__ bo,
                                              float* __restrict__ bvec) {
  int n0 = blockIdx.x * 32;
  int tn = threadIdx.x & 31, tk = threadIdx.x >> 5;
  float acc = 0.f;
  for (int k = tk; k < 5120; k += 8) acc += buv[k] * Wo[(size_t)k * 5120 + n0 + tn];
  __shared__ float red[256];
  red[threadIdx.x] = acc;
  __syncthreads();
  if (tk == 0) {
    float s = 0.f;
#pragma unroll
    for (int i = 0; i < 8; ++i) s += red[i * 32 + tn];
    bvec[n0 + tn] = s + bo[n0 + tn];
  }
}

// ---------------------------------------------------------------------------
// bqabs[h][j] = sum_d b_uq[h*624+d] * W_uk[j][h*624+d]   grid 8, block 128
__global__ __launch_bounds__(128) void k_bqabs(const float* __restrict__ buq,
                                               const float* __restrict__ Wuk,
                                               float* __restrict__ bqabs) {
  int h = blockIdx.x, j = threadIdx.x;
  float acc = 0.f;
  const float* bq = buq + h * 624;
  const float* wk = Wuk + (size_t)j * 4992 + h * 624;
  for (int d = 0; d < 624; ++d) acc += bq[d] * wk[d];
  bqabs[h * 128 + j] = acc;
}

// ---------------------------------------------------------------------------
// wqkT[h][j][i] = sum_d W_uq[i][h*624+d]*W_uk[j][h*624+d]  (fp32, then bf16)
// grid (jt=8, it=8, h=8), block 256 = (i 16 fast, j 16)
__global__ __launch_bounds__(256) void k_wqk(const float* __restrict__ Wuq,
                                             const float* __restrict__ Wuk,
                                             ushort_t* __restrict__ wqkT) {
  __shared__ float Aq[16 * 132];
  __shared__ float Ak[16 * 132];
  int jt = blockIdx.x, it = blockIdx.y, h = blockIdx.z;
  int i0 = it * 16, j0 = jt * 16;
  int t = threadIdx.x;
  int srow = t >> 4, sc0 = (t & 15) * 8;
  int ti = t & 15, tj = t >> 4;
  float acc = 0.f;
  for (int dc = 0; dc < 624; dc += 128) {
#pragma unroll
    for (int i = 0; i < 8; ++i) {
      int d = dc + sc0 + i;
      Aq[srow * 132 + sc0 + i] = (d < 624) ? Wuq[(size_t)(i0 + srow) * 4992 + h * 624 + d] : 0.f;
      Ak[srow * 132 + sc0 + i] = (d < 624) ? Wuk[(size_t)(j0 + srow) * 4992 + h * 624 + d] : 0.f;
    }
    __syncthreads();
    int cs = (624 - dc) < 128 ? (624 - dc) : 128;
    for (int d = 0; d < cs; d += 4) {
      const f32x4 a4 = *(const f32x4*)&Aq[ti * 132 + d];
      const f32x4 b4 = *(const f32x4*)&Ak[tj * 132 + d];
      acc += a4[0] * b4[0] + a4[1] * b4[1] + a4[2] * b4[2] + a4[3] * b4[3];
    }
    __syncthreads();
  }
  wqkT[(size_t)h * 16384 + (size_t)(j0 + tj) * 128 + (i0 + ti)] = f2bf(acc);
}

// ---------------------------------------------------------------------------
// GEMM1: [c_kv | c_q | k_rot(rope)] = h @ [W_dkv|W_dq|W_kr] + bias
// BM=64,BN=128,BK=64. grid (64, 3), block 256 (4 waves 2x2, each 32x64).
__global__ __launch_bounds__(256) void k_gemm1(
    const float* __restrict__ H, const float* __restrict__ Wdkv,
    const float* __restrict__ Wdq, const float* __restrict__ Wkr,
    const float* __restrict__ bdkv, const float* __restrict__ bdq,
    const float* __restrict__ bkr, ushort_t* __restrict__ ckv,
    ushort_t* __restrict__ cq, ushort_t* __restrict__ krot) {
  __shared__ __align__(16) ushort_t As[64 * 72];
  __shared__ __align__(16) ushort_t Bs[128 * 72];
  const int tid = threadIdx.x;
  const int m0 = blockIdx.x * 64;
  const int g = blockIdx.y;
  const float* Wsel = (g == 0) ? Wdkv : (g == 1) ? Wdq : Wkr;
  const int lane = tid & 63, wid = tid >> 6;
  const int quad = lane >> 4, l15 = lane & 15;
  const int wm = wid & 1, wn = wid >> 1;
  f32x4 acc[2][4];
#pragma unroll
  for (int a = 0; a < 2; ++a)
#pragma unroll
    for (int b = 0; b < 4; ++b) acc[a][b] = (f32x4){0.f, 0.f, 0.f, 0.f};
  const int am = tid >> 2, ak0 = (tid & 3) * 16;
  const int bk = tid >> 2, bn0 = (tid & 3) * 32;
  for (int kb = 0; kb < 5120; kb += 64) {
    const float* ap = H + (size_t)(m0 + am) * 5120 + kb + ak0;
    us8 av0, av1;
#pragma unroll
    for (int i = 0; i < 8; ++i) { av0[i] = f2bf(ap[i]); av1[i] = f2bf(ap[8 + i]); }
    *(us8*)&As[am * 72 + ak0] = av0;
    *(us8*)&As[am * 72 + ak0 + 8] = av1;
    const float* bp = Wsel + (size_t)(kb + bk) * 128 + bn0;
#pragma unroll
    for (int i = 0; i < 32; ++i) Bs[(bn0 + i) * 72 + bk] = f2bf(bp[i]);
    __syncthreads();
#pragma unroll
    for (int ks = 0; ks < 2; ++ks) {
      short8 a[2], b[4];
#pragma unroll
      for (int mt = 0; mt < 2; ++mt)
        a[mt] = *(const short8*)&As[(wm * 32 + mt * 16 + l15) * 72 + ks * 32 + quad * 8];
#pragma unroll
      for (int nt = 0; nt < 4; ++nt)
        b[nt] = *(const short8*)&Bs[(wn * 64 + nt * 16 + l15) * 72 + ks * 32 + quad * 8];
#pragma unroll
      for (int mt = 0; mt < 2; ++mt)
#pragma unroll
        for (int nt = 0; nt < 4; ++nt) acc[mt][nt] = MFMA(a[mt], b[nt], acc[mt][nt]);
    }
    __syncthreads();
  }
#pragma unroll
  for (int mt = 0; mt < 2; ++mt)
#pragma unroll
    for (int nt = 0; nt < 4; ++nt) {
      int col = wn * 64 + nt * 16 + l15;
#pragma unroll
      for (int r = 0; r < 4; ++r) {
        int row = m0 + wm * 32 + mt * 16 + quad * 4 + r;
        float v = acc[mt][nt][r];
        if (g == 0) {
          v += bdkv[col];
          ckv[(size_t)row * 128 + col] = f2bf(v);
        } else if (g == 1) {
          v += bdq[col];
          cq[(size_t)row * 128 + col] = f2bf(v);
        } else {
          v += bkr[col];
          float partner = __shfl_xor(v, 4);
          int j = l15;
          int spos = row & 2047;
          int j4 = j & 3;
          float fr = (j4 == 0) ? 1.f : (j4 == 1) ? 0.1f : (j4 == 2) ? 0.01f : 0.001f;
          float sth, cth;
          __sincosf(spos * 0.025f * fr, &sth, &cth);
          float y = (j < 4) ? (v * cth - partner * sth)
                  : (j < 8) ? (v * cth + partner * sth) : v;
          int head = wn * 4 + nt;
          int bb = row >> 11, s = row & 2047;
          krot[((size_t)((bb << 3) + head) * 2048 + s) * 16 + j] = f2bf(y);
        }
      }
    }
}

// ---------------------------------------------------------------------------
// q_rot = rope(c_q @ W_qr + b_qr).  one thread per (b,h,s).  grid 128, block 256.
__global__ __launch_bounds__(256) void k_qrot(const ushort_t* __restrict__ cq,
                                              const float* __restrict__ Wqr,
                                              const float* __restrict__ bqr,
                                              ushort_t* __restrict__ qrot) {
  int gidx = blockIdx.x * 256 + threadIdx.x;  // 0..32767
  int s = gidx & 2047, bh = gidx >> 11;
  int hh = bh & 7, bb = bh >> 3;
  const ushort_t* crow = cq + ((size_t)bb * 2048 + s) * 128;
  float acc[16];
#pragma unroll
  for (int j = 0; j < 16; ++j) acc[j] = bqr[hh * 16 + j];
  for (int k0 = 0; k0 < 128; k0 += 8) {
    us8 cv8 = *(const us8*)(crow + k0);
#pragma unroll
    for (int i = 0; i < 8; ++i) {
      float cv = bf2f(cv8[i]);
      const float* wr = Wqr + (size_t)(k0 + i) * 128 + hh * 16;
#pragma unroll
      for (int j = 0; j < 16; ++j) acc[j] += cv * wr[j];
    }
  }
  float y[16];
#pragma unroll
  for (int j4 = 0; j4 < 4; ++j4) {
    float fr = (j4 == 0) ? 1.f : (j4 == 1) ? 0.1f : (j4 == 2) ? 0.01f : 0.001f;
    float sth, cth;
    __sincosf(s * 0.025f * fr, &sth, &cth);
    y[j4] = acc[j4] * cth - acc[j4 + 4] * sth;
    y[j4 + 4] = acc[j4 + 4] * cth + acc[j4] * sth;
  }
#pragma unroll
  for (int j = 8; j < 16; ++j) y[j] = acc[j];
  us8 o0, o1;
#pragma unroll
  for (int j = 0; j < 8; ++j) { o0[j] = f2bf(y[j]); o1[j] = f2bf(y[8 + j]); }
  *(us8*)(qrot + (size_t)gidx * 16) = o0;
  *(us8*)(qrot + (size_t)gidx * 16 + 8) = o1;
}

// ---------------------------------------------------------------------------
// q_abs = c_q @ W_qk[h] + b_qabs[h].  BM=128,BN=128,BK=64. grid (32, 8).
__global__ __launch_bounds__(256) void k_qabs(const ushort_t* __restrict__ cq,
                                              const ushort_t* __restrict__ wqkT,
                                              const float* __restrict__ bqabs,
                                              ushort_t* __restrict__ qabs) {
  __shared__ __align__(16) ushort_t As[128 * 72];
  __shared__ __align__(16) ushort_t Bs[128 * 72];
  const int tid = threadIdx.x;
  const int m0 = blockIdx.x * 128, hh = blockIdx.y;
  const int lane = tid & 63, wid = tid >> 6;
  const int quad = lane >> 4, l15 = lane & 15;
  const int wm = wid & 1, wn = wid >> 1;
  f32x4 acc[4][4];
#pragma unroll
  for (int a = 0; a < 4; ++a)
#pragma unroll
    for (int b = 0; b < 4; ++b) acc[a][b] = (f32x4){0.f, 0.f, 0.f, 0.f};
  const int ar = tid >> 1, as0 = (tid & 1) * 32;
  for (int kb = 0; kb < 128; kb += 64) {
    const ushort_t* ap = cq + (size_t)(m0 + ar) * 128 + kb + as0;
    const ushort_t* bp = wqkT + (size_t)hh * 16384 + (size_t)ar * 128 + kb + as0;
#pragma unroll
    for (int w = 0; w < 4; ++w) {
      *(us8*)&As[ar * 72 + as0 + w * 8] = *(const us8*)(ap + w * 8);
      *(us8*)&Bs[ar * 72 + as0 + w * 8] = *(const us8*)(bp + w * 8);
    }
    __syncthreads();
#pragma unroll
    for (int ks = 0; ks < 2; ++ks) {
      short8 a[4], b[4];
#pragma unroll
      for (int mt = 0; mt < 4; ++mt)
        a[mt] = *(const short8*)&As[(wm * 64 + mt * 16 + l15) * 72 + ks * 32 + quad * 8];
#pragma unroll
      for (int nt = 0; nt < 4; ++nt)
        b[nt] = *(const short8*)&Bs[(wn * 64 + nt * 16 + l15) * 72 + ks * 32 + quad * 8];
#pragma unroll
      for (int mt = 0; mt < 4; ++mt)
#pragma unroll
        for (int nt = 0; nt < 4; ++nt) acc[mt][nt] = MFMA(a[mt], b[nt], acc[mt][nt]);
    }
    __syncthreads();
  }
#pragma unroll
  for (int mt = 0; mt < 4; ++mt)
#pragma unroll
    for (int nt = 0; nt < 4; ++nt) {
      int col = wn * 64 + nt * 16 + l15;
      float bias = bqabs[hh * 128 + col];
#pragma unroll
      for (int r = 0; r < 4; ++r) {
        int m = m0 + wm * 64 + mt * 16 + quad * 4 + r;
        int bb = m >> 11, s = m & 2047;
        qabs[((size_t)((bb << 3) + hh) * 2048 + s) * 128 + col] = f2bf(acc[mt][nt][r] + bias);
      }
    }
}

// ---------------------------------------------------------------------------
// wcombT[n][h*128+c] = sum_d W_o[h*640+d][n] * W_uv[c][h*640+d]
// BM(n)=128, BN(c)=128, BK(d)=64, K=640. grid (40, 8).
__global__ __launch_bounds__(256) void k_comb(const float* __restrict__ Wo,
                                              const float* __restrict__ Wuv,
                                              ushort_t* __restrict__ wcombT) {
  __shared__ __align__(16) ushort_t As[128 * 72];
  __shared__ __align__(16) ushort_t Bs[128 * 72];
  const int tid = threadIdx.x;
  const int n0 = blockIdx.x * 128, hh = blockIdx.y;
  const int lane = tid & 63, wid = tid >> 6;
  const int quad = lane >> 4, l15 = lane & 15;
  const int wm = wid & 1, wn = wid >> 1;
  f32x4 acc[4][4];
#pragma unroll
  for (int a = 0; a < 4; ++a)
#pragma unroll
    for (int b = 0; b < 4; ++b) acc[a][b] = (f32x4){0.f, 0.f, 0.f, 0.f};
  const int ad = tid >> 2, an0 = (tid & 3) * 32;
  const int bc = tid >> 1, bd0 = (tid & 1) * 32;
  for (int kb = 0; kb < 640; kb += 64) {
    const float* ap = Wo + (size_t)(hh * 640 + kb + ad) * 5120 + n0 + an0;
#pragma unroll
    for (int i = 0; i < 32; ++i) As[(an0 + i) * 72 + ad] = f2bf(ap[i]);
    const float* bp = Wuv + (size_t)bc * 5120 + hh * 640 + kb + bd0;
    us8 bv0, bv1, bv2, bv3;
#pragma unroll
    for (int i = 0; i < 8; ++i) {
      bv0[i] = f2bf(bp[i]); bv1[i] = f2bf(bp[8 + i]);
      bv2[i] = f2bf(bp[16 + i]); bv3[i] = f2bf(bp[24 + i]);
    }
    *(us8*)&Bs[bc * 72 + bd0] = bv0;
    *(us8*)&Bs[bc * 72 + bd0 + 8] = bv1;
    *(us8*)&Bs[bc * 72 + bd0 + 16] = bv2;
    *(us8*)&Bs[bc * 72 + bd0 + 24] = bv3;
    __syncthreads();
#pragma unroll
    for (int ks = 0; ks < 2; ++ks) {
      short8 a[4], b[4];
#pragma unroll
      for (int mt = 0; mt < 4; ++mt)
        a[mt] = *(const short8*)&As[(wm * 64 + mt * 16 + l15) * 72 + ks * 32 + quad * 8];
#pragma unroll
      for (int nt = 0; nt < 4; ++nt)
        b[nt] = *(const short8*)&Bs[(wn * 64 + nt * 16 + l15) * 72 + ks * 32 + quad * 8];
#pragma unroll
      for (int mt = 0; mt < 4; ++mt)
#pragma unroll
        for (int nt = 0; nt < 4; ++nt) acc[mt][nt] = MFMA(a[mt], b[nt], acc[mt][nt]);
    }
    __syncthreads();
  }
#pragma unroll
  for (int mt = 0; mt < 4; ++mt)
#pragma unroll
    for (int nt = 0; nt < 4; ++nt) {
      int col = wn * 64 + nt * 16 + l15;
#pragma unroll
      for (int r = 0; r < 4; ++r) {
        int n = n0 + wm * 64 + mt * 16 + quad * 4 + r;
        wcombT[(size_t)n * 1024 + hh * 128 + col] = f2bf(acc[mt][nt][r]);
      }
    }
}

// ---------------------------------------------------------------------------
// Flash attention over absorbed dims. grid (32 q-tiles, 16 bh), block 256.
// Q/K 144-dim (pad->160), V = c_kv (128). ctx out bf16 (b,s,h,128).
__global__ __launch_bounds__(256) void k_attn(const ushort_t* __restrict__ qabs,
                                              const ushort_t* __restrict__ qrot,
                                              const ushort_t* __restrict__ ckv,
                                              const ushort_t* __restrict__ krot,
                                              ushort_t* __restrict__ ctx) {
  __shared__ __align__(16) ushort_t Qs[64 * 160];
  __shared__ __align__(16) ushort_t Ks[64 * 160];
  __shared__ __align__(16) ushort_t Vt[128 * 72];
  __shared__ __align__(16) ushort_t Ps[64 * 72];
  const int tid = threadIdx.x;
  const int bh = blockIdx.y, bb = bh >> 3, hh = bh & 7;
  const int q0 = blockIdx.x * 64;
  const int lane = tid & 63, wid = tid >> 6;
  const int quad = lane >> 4, l15 = lane & 15;
  const int sr = tid >> 2, sseg = tid & 3;
  {
    const ushort_t* qa = qabs + ((size_t)bh * 2048 + q0 + sr) * 128 + sseg * 32;
#pragma unroll
    for (int w = 0; w < 4; ++w)
      *(us8*)&Qs[sr * 160 + sseg * 32 + w * 8] = *(const us8*)(qa + w * 8);
    if (sseg == 0) {
      const ushort_t* qr = qrot + ((size_t)bh * 2048 + q0 + sr) * 16;
      *(us8*)&Qs[sr * 160 + 128] = *(const us8*)qr;
      *(us8*)&Qs[sr * 160 + 136] = *(const us8*)(qr + 8);
    }
    if (sseg == 1) {
      us8 z = (us8)0;
      *(us8*)&Qs[sr * 160 + 144] = z;
      *(us8*)&Qs[sr * 160 + 152] = z;
    }
  }
  f32x4 oacc[8];
#pragma unroll
  for (int i = 0; i < 8; ++i) oacc[i] = (f32x4){0.f, 0.f, 0.f, 0.f};
  float mrow[4] = {-1e30f, -1e30f, -1e30f, -1e30f};
  float lrow[4] = {0.f, 0.f, 0.f, 0.f};

  for (int kt = 0; kt < 32; ++kt) {
    int key0 = kt * 64;
    {
      const ushort_t* kp = ckv + ((size_t)bb * 2048 + key0 + sr) * 128 + sseg * 32;
      us8 v[4];
#pragma unroll
      for (int w = 0; w < 4; ++w) v[w] = *(const us8*)(kp + w * 8);
#pragma unroll
      for (int w = 0; w < 4; ++w)
        *(us8*)&Ks[sr * 160 + sseg * 32 + w * 8] = v[w];
#pragma unroll
      for (int w = 0; w < 4; ++w)
#pragma unroll
        for (int i = 0; i < 8; ++i)
          Vt[(sseg * 32 + w * 8 + i) * 72 + sr] = v[w][i];
      if (sseg == 0) {
        const ushort_t* kr = krot + ((size_t)bh * 2048 + key0 + sr) * 16;
        *(us8*)&Ks[sr * 160 + 128] = *(const us8*)kr;
        *(us8*)&Ks[sr * 160 + 136] = *(const us8*)(kr + 8);
      }
      if (sseg == 1) {
        us8 z = (us8)0;
        *(us8*)&Ks[sr * 160 + 144] = z;
        *(us8*)&Ks[sr * 160 + 152] = z;
      }
    }
    __syncthreads();
    // ---- QK^T (144 real + 16 zero dims)
    f32x4 sacc[4];
#pragma unroll
    for (int nt = 0; nt < 4; ++nt) sacc[nt] = (f32x4){0.f, 0.f, 0.f, 0.f};
#pragma unroll
    for (int ks = 0; ks < 5; ++ks) {
      short8 aq = *(const short8*)&Qs[(wid * 16 + l15) * 160 + ks * 32 + quad * 8];
#pragma unroll
      for (int nt = 0; nt < 4; ++nt) {
        short8 bk = *(const short8*)&Ks[(nt * 16 + l15) * 160 + ks * 32 + quad * 8];
        sacc[nt] = MFMA(aq, bk, sacc[nt]);
      }
    }
    // ---- online softmax (each wave owns complete score rows)
    float p[4][4];
#pragma unroll
    for (int r = 0; r < 4; ++r) {
      float mx = -1e30f;
#pragma unroll
      for (int nt = 0; nt < 4; ++nt) {
        sacc[nt][r] *= SCALE_ATT;
        mx = fmaxf(mx, sacc[nt][r]);
      }
#pragma unroll
      for (int off = 1; off < 16; off <<= 1) mx = fmaxf(mx, __shfl_xor(mx, off));
      float mnew = fmaxf(mrow[r], mx);
      float alpha = __expf(mrow[r] - mnew);
      mrow[r] = mnew;
      float rs = 0.f;
#pragma unroll
      for (int nt = 0; nt < 4; ++nt) {
        float pv = __expf(sacc[nt][r] - mnew);
        p[nt][r] = pv;
        rs += pv;
      }
#pragma unroll
      for (int off = 1; off < 16; off <<= 1) rs += __shfl_xor(rs, off);
      lrow[r] = lrow[r] * alpha + rs;
#pragma unroll
      for (int t8 = 0; t8 < 8; ++t8) oacc[t8][r] *= alpha;
    }
#pragma unroll
    for (int nt = 0; nt < 4; ++nt)
#pragma unroll
      for (int r = 0; r < 4; ++r)
        Ps[(wid * 16 + quad * 4 + r) * 72 + nt * 16 + l15] = f2bf(p[nt][r]);
    __syncthreads();
    // ---- PV: oacc += P(16x64) @ c_kv_tile(64x128)
#pragma unroll
    for (int kk = 0; kk < 2; ++kk) {
      short8 pa = *(const short8*)&Ps[(wid * 16 + l15) * 72 + kk * 32 + quad * 8];
#pragma unroll
      for (int nt = 0; nt < 8; ++nt) {
        short8 vb = *(const short8*)&Vt[(nt * 16 + l15) * 72 + kk * 32 + quad * 8];
        oacc[nt] = MFMA(pa, vb, oacc[nt]);
      }
    }
    __syncthreads();
  }
#pragma unroll
  for (int r = 0; r < 4; ++r) {
    float rl = 1.f / lrow[r];
    int row = q0 + wid * 16 + quad * 4 + r;
    size_t base = ((size_t)bb * 2048 + row) * 1024 + hh * 128;
#pragma unroll
    for (int nt = 0; nt < 8; ++nt)
      ctx[base + nt * 16 + l15] = f2bf(oacc[nt][r] * rl);
  }
}

// ---------------------------------------------------------------------------
// out = ctx(4096x1024) @ wcombT^T + bvec.  BM=BN=128, BK=64, K=1024. grid (32,40)
__global__ __launch_bounds__(256) void k_final(const ushort_t* __restrict__ ctx,
                                               const ushort_t* __restrict__ wcombT,
                                               const float* __restrict__ bvec,
                                               float* __restrict__ out) {
  __shared__ __align__(16) ushort_t As[128 * 72];
  __shared__ __align__(16) ushort_t Bs[128 * 72];
  const int tid = threadIdx.x;
  const int m0 = blockIdx.x * 128, n0 = blockIdx.y * 128;
  const int lane = tid & 63, wid = tid >> 6;
  const int quad = lane >> 4, l15 = lane & 15;
  const int wm = wid & 1, wn = wid >> 1;
  f32x4 acc[4][4];
#pragma unroll
  for (int a = 0; a < 4; ++a)
#pragma unroll
    for (int b = 0; b < 4; ++b) acc[a][b] = (f32x4){0.f, 0.f, 0.f, 0.f};
  const int ar = tid >> 1, as0 = (tid & 1) * 32;
  for (int kb = 0; kb < 1024; kb += 64) {
    const ushort_t* ap = ctx + (size_t)(m0 + ar) * 1024 + kb + as0;
    const ushort_t* bp = wcombT + (size_t)(n0 + ar) * 1024 + kb + as0;
#pragma unroll
    for (int w = 0; w < 4; ++w) {
      *(us8*)&As[ar * 72 + as0 + w * 8] = *(const us8*)(ap + w * 8);
      *(us8*)&Bs[ar * 72 + as0 + w * 8] = *(const us8*)(bp + w * 8);
    }
    __syncthreads();
#pragma unroll
    for (int ks = 0; ks < 2; ++ks) {
      short8 a[4], b[4];
#pragma unroll
      for (int mt = 0; mt < 4; ++mt)
        a[mt] = *(const short8*)&As[(wm * 64 + mt * 16 + l15) * 72 + ks * 32 + quad * 8];
#pragma unroll
      for (int nt = 0; nt < 4; ++nt)
        b[nt] = *(const short8*)&Bs[(wn * 64 + nt * 16 + l15) * 72 + ks * 32 + quad * 8];
#pragma unroll
      for (int mt = 0; mt < 4; ++mt)
#pragma unroll
        for (int nt = 0; nt < 4; ++nt) acc[mt][nt] = MFMA(a[mt], b[nt], acc[mt][nt]);
    }
    __syncthreads();
  }
#pragma unroll
  for (int mt = 0; mt < 4; ++mt)
#pragma unroll
    for (int nt = 0; nt < 4; ++nt) {
      int col = wn * 64 + nt * 16 + l15;
      float bias = bvec[n0 + col];
#pragma unroll
      for (int r = 0; r < 4; ++r) {
        int row = m0 + wm * 64 + mt * 16 + quad * 4 + r;
        out[(size_t)row * 5120 + n0 + col] = acc[mt][nt][r] + bias;
      }
    }
}

// ---------------------------------------------------------------------------
extern "C" void kernel_launch(void* const* d_in, const int* in_sizes, int n_in,
                              void* d_out, int out_size, void* d_ws, size_t ws_size,
                              hipStream_t stream) {
  const float* H    = (const float*)d_in[0];
  const float* Wdkv = (const float*)d_in[1];
  const float* bdkv = (const float*)d_in[2];
  const float* Wdq  = (const float*)d_in[3];
  const float* bdq  = (const float*)d_in[4];
  const float* Wuk  = (const float*)d_in[5];
  // d_in[6] = b_uk : softmax-invariant (constant per score row) -> unused
  const float* Wuv  = (const float*)d_in[7];
  const float* buv  = (const float*)d_in[8];
  const float* Wuq  = (const float*)d_in[9];
  const float* buq  = (const float*)d_in[10];
  const float* Wqr  = (const float*)d_in[11];
  const float* bqr  = (const float*)d_in[12];
  const float* Wkr  = (const float*)d_in[13];
  const float* bkr  = (const float*)d_in[14];
  const float* Wo   = (const float*)d_in[15];
  const float* bo   = (const float*)d_in[16];
  float* out = (float*)d_out;

  char* ws = (char*)d_ws;
  size_t off = 0;
  auto alloc = [&](size_t bytes) -> void* {
    void* p = ws + off;
    off += (bytes + 255) & ~(size_t)255;
    return p;
  };
  ushort_t* ckv    = (ushort_t*)alloc((size_t)4096 * 128 * 2);
  ushort_t* cq     = (ushort_t*)alloc((size_t)4096 * 128 * 2);
  ushort_t* krot   = (ushort_t*)alloc((size_t)16 * 2048 * 16 * 2);
  ushort_t* qrot   = (ushort_t*)alloc((size_t)16 * 2048 * 16 * 2);
  ushort_t* qabs   = (ushort_t*)alloc((size_t)16 * 2048 * 128 * 2);
  ushort_t* wqkT   = (ushort_t*)alloc((size_t)8 * 128 * 128 * 2);
  float*    bqabs  = (float*)alloc((size_t)8 * 128 * 4);
  ushort_t* wcombT = (ushort_t*)alloc((size_t)5120 * 1024 * 2);
  float*    bvec   = (float*)alloc((size_t)5120 * 4);
  ushort_t* ctx    = (ushort_t*)alloc((size_t)4096 * 1024 * 2);
  (void)ws_size; (void)in_sizes; (void)n_in; (void)out_size;

  hipLaunchKernelGGL(k_bvec, dim3(160), dim3(256), 0, stream, buv, Wo, bo, bvec);
  hipLaunchKernelGGL(k_bqabs, dim3(8), dim3(128), 0, stream, buq, Wuk, bqabs);
  hipLaunchKernelGGL(k_wqk, dim3(8, 8, 8), dim3(256), 0, stream, Wuq, Wuk, wqkT);
  hipLaunchKernelGGL(k_gemm1, dim3(64, 3), dim3(256), 0, stream,
                     H, Wdkv, Wdq, Wkr, bdkv, bdq, bkr, ckv, cq, krot);
  hipLaunchKernelGGL(k_comb, dim3(40, 8), dim3(256), 0, stream, Wo, Wuv, wcombT);
  hipLaunchKernelGGL(k_qrot, dim3(128), dim3(256), 0, stream, cq, Wqr, bqr, qrot);
  hipLaunchKernelGGL(k_qabs, dim3(32, 8), dim3(256), 0, stream, cq, wqkT, bqabs, qabs);
  hipLaunchKernelGGL(k_attn, dim3(32, 16), dim3(256), 0, stream, qabs, qrot, ckv, krot, ctx);
  hipLaunchKernelGGL(k_final, dim3(32, 40), dim3(256), 0, stream, ctx, wcombT, bvec, out);
}

// Round 2
// 849.585 us; speedup vs baseline: 1.2875x; 1.2875x over previous
//
#include <hip/hip_runtime.h>

// ---------------------------------------------------------------------------
// MemoryOptimizedMLA on gfx950 — absorbed-MLA formulation.
//
//   c_kv = h@W_dkv+b ; c_q = h@W_dq+b ; k_rot = rope(h@W_kr+b)
//   W_qk[h] = W_uq_h @ W_uk_h^T (128x128), b_qabs[h] = b_uq_h @ W_uk_h^T
//   q_abs = c_q@W_qk + b_qabs ; q_rot = rope(c_q@W_qr + b_qr)
//   scores = (q_abs . c_kv + q_rot . k_rot)/sqrt(640)   (b_uk is softmax-inv.)
//   ctx = softmax(scores) @ c_kv      (128 dims, flash/online-softmax)
//   out = ctx @ W_combT^T + (b_uv@W_o + b_o),  W_comb[h] = W_uv_h @ W_o_h
// ---------------------------------------------------------------------------

typedef unsigned short ushort_t;
typedef __attribute__((ext_vector_type(8)))  short          short8;
typedef __attribute__((ext_vector_type(8)))  unsigned short us8;
typedef __attribute__((ext_vector_type(4)))  float          f32x4;

#define SCALE_ATT 0.0395284707521047f  /* 1/sqrt(640) */

static __device__ inline unsigned short f2bf(float f) {
  union { float f; unsigned u; } v; v.f = f;
  unsigned r = (v.u + 0x7fffu + ((v.u >> 16) & 1u)) >> 16;
  return (unsigned short)r;
}
static __device__ inline float bf2f(unsigned short u) {
  union { unsigned u; float f; } v; v.u = ((unsigned)u) << 16;
  return v.f;
}
static __device__ inline f32x4 MFMA(short8 a, short8 b, f32x4 c) {
  return __builtin_amdgcn_mfma_f32_16x16x32_bf16(a, b, c, 0, 0, 0);
}

// ---------------------------------------------------------------------------
// bvec init: bvec[n] = bo[n].  grid 20, block 256.
__global__ __launch_bounds__(256) void k_bvec_init(const float* __restrict__ bo,
                                                   float* __restrict__ bvec) {
  int n = blockIdx.x * 256 + threadIdx.x;
  bvec[n] = bo[n];
}

// bvec accumulate: bvec[n] += sum_k buv[k]*Wo[k][n].
// grid (5 n-tiles x 64 k-tiles), block 256; thread owns float4 of columns.
// Coalesced 16B/lane row-streaming; 104 MB total read -> ~20 us at BW ceiling.
__global__ __launch_bounds__(256) void k_bvec_acc(const float* __restrict__ buv,
                                                  const float* __restrict__ Wo,
                                                  float* __restrict__ bvec) {
  const int n0 = blockIdx.x * 1024 + threadIdx.x * 4;
  const int k0 = blockIdx.y * 80;
  f32x4 acc = (f32x4){0.f, 0.f, 0.f, 0.f};
  const float* wp = Wo + (size_t)k0 * 5120 + n0;
#pragma unroll 4
  for (int k = 0; k < 80; ++k) {
    float bv = buv[k0 + k];
    const f32x4 w = *(const f32x4*)wp;
    acc[0] += bv * w[0]; acc[1] += bv * w[1];
    acc[2] += bv * w[2]; acc[3] += bv * w[3];
    wp += 5120;
  }
  atomicAdd(&bvec[n0 + 0], acc[0]);
  atomicAdd(&bvec[n0 + 1], acc[1]);
  atomicAdd(&bvec[n0 + 2], acc[2]);
  atomicAdd(&bvec[n0 + 3], acc[3]);
}

// ---------------------------------------------------------------------------
// bqabs[h][j] = sum_d b_uq[h*624+d] * W_uk[j][h*624+d]   grid 8, block 128
__global__ __launch_bounds__(128) void k_bqabs(const float* __restrict__ buq,
                                               const float* __restrict__ Wuk,
                                               float* __restrict__ bqabs) {
  int h = blockIdx.x, j = threadIdx.x;
  float acc = 0.f;
  const float* bq = buq + h * 624;
  const float* wk = Wuk + (size_t)j * 4992 + h * 624;
  for (int d = 0; d < 624; ++d) acc += bq[d] * wk[d];
  bqabs[h * 128 + j] = acc;
}

// ---------------------------------------------------------------------------
// wqkT[h][j][i] = sum_d W_uq[i][h*624+d]*W_uk[j][h*624+d]  (fp32, then bf16)
// grid (jt=8, it=8, h=8), block 256 = (i 16 fast, j 16)
__global__ __launch_bounds__(256) void k_wqk(const float* __restrict__ Wuq,
                                             const float* __restrict__ Wuk,
                                             ushort_t* __restrict__ wqkT) {
  __shared__ float Aq[16 * 132];
  __shared__ float Ak[16 * 132];
  int jt = blockIdx.x, it = blockIdx.y, h = blockIdx.z;
  int i0 = it * 16, j0 = jt * 16;
  int t = threadIdx.x;
  int srow = t >> 4, sc0 = (t & 15) * 8;
  int ti = t & 15, tj = t >> 4;
  float acc = 0.f;
  for (int dc = 0; dc < 624; dc += 128) {
#pragma unroll
    for (int i = 0; i < 8; ++i) {
      int d = dc + sc0 + i;
      Aq[srow * 132 + sc0 + i] = (d < 624) ? Wuq[(size_t)(i0 + srow) * 4992 + h * 624 + d] : 0.f;
      Ak[srow * 132 + sc0 + i] = (d < 624) ? Wuk[(size_t)(j0 + srow) * 4992 + h * 624 + d] : 0.f;
    }
    __syncthreads();
    int cs = (624 - dc) < 128 ? (624 - dc) : 128;
    for (int d = 0; d < cs; d += 4) {
      const f32x4 a4 = *(const f32x4*)&Aq[ti * 132 + d];
      const f32x4 b4 = *(const f32x4*)&Ak[tj * 132 + d];
      acc += a4[0] * b4[0] + a4[1] * b4[1] + a4[2] * b4[2] + a4[3] * b4[3];
    }
    __syncthreads();
  }
  wqkT[(size_t)h * 16384 + (size_t)(j0 + tj) * 128 + (i0 + ti)] = f2bf(acc);
}

// ---------------------------------------------------------------------------
// GEMM1: [c_kv | c_q | k_rot(rope)] = h @ [W_dkv|W_dq|W_kr] + bias
// BM=64,BN=128,BK=64. grid (64, 3), block 256 (4 waves 2x2, each 32x64).
__global__ __launch_bounds__(256) void k_gemm1(
    const float* __restrict__ H, const float* __restrict__ Wdkv,
    const float* __restrict__ Wdq, const float* __restrict__ Wkr,
    const float* __restrict__ bdkv, const float* __restrict__ bdq,
    const float* __restrict__ bkr, ushort_t* __restrict__ ckv,
    ushort_t* __restrict__ cq, ushort_t* __restrict__ krot) {
  __shared__ __align__(16) ushort_t As[64 * 72];
  __shared__ __align__(16) ushort_t Bs[128 * 72];
  const int tid = threadIdx.x;
  const int m0 = blockIdx.x * 64;
  const int g = blockIdx.y;
  const float* Wsel = (g == 0) ? Wdkv : (g == 1) ? Wdq : Wkr;
  const int lane = tid & 63, wid = tid >> 6;
  const int quad = lane >> 4, l15 = lane & 15;
  const int wm = wid & 1, wn = wid >> 1;
  f32x4 acc[2][4];
#pragma unroll
  for (int a = 0; a < 2; ++a)
#pragma unroll
    for (int b = 0; b < 4; ++b) acc[a][b] = (f32x4){0.f, 0.f, 0.f, 0.f};
  const int am = tid >> 2, ak0 = (tid & 3) * 16;
  const int bk = tid >> 2, bn0 = (tid & 3) * 32;
  for (int kb = 0; kb < 5120; kb += 64) {
    const float* ap = H + (size_t)(m0 + am) * 5120 + kb + ak0;
    us8 av0, av1;
#pragma unroll
    for (int i = 0; i < 8; ++i) { av0[i] = f2bf(ap[i]); av1[i] = f2bf(ap[8 + i]); }
    *(us8*)&As[am * 72 + ak0] = av0;
    *(us8*)&As[am * 72 + ak0 + 8] = av1;
    const float* bp = Wsel + (size_t)(kb + bk) * 128 + bn0;
#pragma unroll
    for (int i = 0; i < 32; ++i) Bs[(bn0 + i) * 72 + bk] = f2bf(bp[i]);
    __syncthreads();
#pragma unroll
    for (int ks = 0; ks < 2; ++ks) {
      short8 a[2], b[4];
#pragma unroll
      for (int mt = 0; mt < 2; ++mt)
        a[mt] = *(const short8*)&As[(wm * 32 + mt * 16 + l15) * 72 + ks * 32 + quad * 8];
#pragma unroll
      for (int nt = 0; nt < 4; ++nt)
        b[nt] = *(const short8*)&Bs[(wn * 64 + nt * 16 + l15) * 72 + ks * 32 + quad * 8];
#pragma unroll
      for (int mt = 0; mt < 2; ++mt)
#pragma unroll
        for (int nt = 0; nt < 4; ++nt) acc[mt][nt] = MFMA(a[mt], b[nt], acc[mt][nt]);
    }
    __syncthreads();
  }
#pragma unroll
  for (int mt = 0; mt < 2; ++mt)
#pragma unroll
    for (int nt = 0; nt < 4; ++nt) {
      int col = wn * 64 + nt * 16 + l15;
#pragma unroll
      for (int r = 0; r < 4; ++r) {
        int row = m0 + wm * 32 + mt * 16 + quad * 4 + r;
        float v = acc[mt][nt][r];
        if (g == 0) {
          v += bdkv[col];
          ckv[(size_t)row * 128 + col] = f2bf(v);
        } else if (g == 1) {
          v += bdq[col];
          cq[(size_t)row * 128 + col] = f2bf(v);
        } else {
          v += bkr[col];
          float partner = __shfl_xor(v, 4);
          int j = l15;
          int spos = row & 2047;
          int j4 = j & 3;
          float fr = (j4 == 0) ? 1.f : (j4 == 1) ? 0.1f : (j4 == 2) ? 0.01f : 0.001f;
          float sth, cth;
          __sincosf(spos * 0.025f * fr, &sth, &cth);
          float y = (j < 4) ? (v * cth - partner * sth)
                  : (j < 8) ? (v * cth + partner * sth) : v;
          int head = wn * 4 + nt;
          int bb = row >> 11, s = row & 2047;
          krot[((size_t)((bb << 3) + head) * 2048 + s) * 16 + j] = f2bf(y);
        }
      }
    }
}

// ---------------------------------------------------------------------------
// q_rot = rope(c_q @ W_qr + b_qr).  one thread per (b,h,s).  grid 128, block 256.
__global__ __launch_bounds__(256) void k_qrot(const ushort_t* __restrict__ cq,
                                              const float* __restrict__ Wqr,
                                              const float* __restrict__ bqr,
                                              ushort_t* __restrict__ qrot) {
  int gidx = blockIdx.x * 256 + threadIdx.x;  // 0..32767
  int s = gidx & 2047, bh = gidx >> 11;
  int hh = bh & 7, bb = bh >> 3;
  const ushort_t* crow = cq + ((size_t)bb * 2048 + s) * 128;
  float acc[16];
#pragma unroll
  for (int j = 0; j < 16; ++j) acc[j] = bqr[hh * 16 + j];
  for (int k0 = 0; k0 < 128; k0 += 8) {
    us8 cv8 = *(const us8*)(crow + k0);
#pragma unroll
    for (int i = 0; i < 8; ++i) {
      float cv = bf2f(cv8[i]);
      const float* wr = Wqr + (size_t)(k0 + i) * 128 + hh * 16;
#pragma unroll
      for (int j = 0; j < 16; ++j) acc[j] += cv * wr[j];
    }
  }
  float y[16];
#pragma unroll
  for (int j4 = 0; j4 < 4; ++j4) {
    float fr = (j4 == 0) ? 1.f : (j4 == 1) ? 0.1f : (j4 == 2) ? 0.01f : 0.001f;
    float sth, cth;
    __sincosf(s * 0.025f * fr, &sth, &cth);
    y[j4] = acc[j4] * cth - acc[j4 + 4] * sth;
    y[j4 + 4] = acc[j4 + 4] * cth + acc[j4] * sth;
  }
#pragma unroll
  for (int j = 8; j < 16; ++j) y[j] = acc[j];
  us8 o0, o1;
#pragma unroll
  for (int j = 0; j < 8; ++j) { o0[j] = f2bf(y[j]); o1[j] = f2bf(y[8 + j]); }
  *(us8*)(qrot + (size_t)gidx * 16) = o0;
  *(us8*)(qrot + (size_t)gidx * 16 + 8) = o1;
}

// ---------------------------------------------------------------------------
// q_abs = c_q @ W_qk[h] + b_qabs[h].  BM=128,BN=128,BK=64. grid (32, 8).
__global__ __launch_bounds__(256) void k_qabs(const ushort_t* __restrict__ cq,
                                              const ushort_t* __restrict__ wqkT,
                                              const float* __restrict__ bqabs,
                                              ushort_t* __restrict__ qabs) {
  __shared__ __align__(16) ushort_t As[128 * 72];
  __shared__ __align__(16) ushort_t Bs[128 * 72];
  const int tid = threadIdx.x;
  const int m0 = blockIdx.x * 128, hh = blockIdx.y;
  const int lane = tid & 63, wid = tid >> 6;
  const int quad = lane >> 4, l15 = lane & 15;
  const int wm = wid & 1, wn = wid >> 1;
  f32x4 acc[4][4];
#pragma unroll
  for (int a = 0; a < 4; ++a)
#pragma unroll
    for (int b = 0; b < 4; ++b) acc[a][b] = (f32x4){0.f, 0.f, 0.f, 0.f};
  const int ar = tid >> 1, as0 = (tid & 1) * 32;
  for (int kb = 0; kb < 128; kb += 64) {
    const ushort_t* ap = cq + (size_t)(m0 + ar) * 128 + kb + as0;
    const ushort_t* bp = wqkT + (size_t)hh * 16384 + (size_t)ar * 128 + kb + as0;
#pragma unroll
    for (int w = 0; w < 4; ++w) {
      *(us8*)&As[ar * 72 + as0 + w * 8] = *(const us8*)(ap + w * 8);
      *(us8*)&Bs[ar * 72 + as0 + w * 8] = *(const us8*)(bp + w * 8);
    }
    __syncthreads();
#pragma unroll
    for (int ks = 0; ks < 2; ++ks) {
      short8 a[4], b[4];
#pragma unroll
      for (int mt = 0; mt < 4; ++mt)
        a[mt] = *(const short8*)&As[(wm * 64 + mt * 16 + l15) * 72 + ks * 32 + quad * 8];
#pragma unroll
      for (int nt = 0; nt < 4; ++nt)
        b[nt] = *(const short8*)&Bs[(wn * 64 + nt * 16 + l15) * 72 + ks * 32 + quad * 8];
#pragma unroll
      for (int mt = 0; mt < 4; ++mt)
#pragma unroll
        for (int nt = 0; nt < 4; ++nt) acc[mt][nt] = MFMA(a[mt], b[nt], acc[mt][nt]);
    }
    __syncthreads();
  }
#pragma unroll
  for (int mt = 0; mt < 4; ++mt)
#pragma unroll
    for (int nt = 0; nt < 4; ++nt) {
      int col = wn * 64 + nt * 16 + l15;
      float bias = bqabs[hh * 128 + col];
#pragma unroll
      for (int r = 0; r < 4; ++r) {
        int m = m0 + wm * 64 + mt * 16 + quad * 4 + r;
        int bb = m >> 11, s = m & 2047;
        qabs[((size_t)((bb << 3) + hh) * 2048 + s) * 128 + col] = f2bf(acc[mt][nt][r] + bias);
      }
    }
}

// ---------------------------------------------------------------------------
// wcombT[n][h*128+c] = sum_d W_o[h*640+d][n] * W_uv[c][h*640+d]
// BM(n)=128, BN(c)=128, BK(d)=64, K=640. grid (40, 8).
__global__ __launch_bounds__(256) void k_comb(const float* __restrict__ Wo,
                                              const float* __restrict__ Wuv,
                                              ushort_t* __restrict__ wcombT) {
  __shared__ __align__(16) ushort_t As[128 * 72];
  __shared__ __align__(16) ushort_t Bs[128 * 72];
  const int tid = threadIdx.x;
  const int n0 = blockIdx.x * 128, hh = blockIdx.y;
  const int lane = tid & 63, wid = tid >> 6;
  const int quad = lane >> 4, l15 = lane & 15;
  const int wm = wid & 1, wn = wid >> 1;
  f32x4 acc[4][4];
#pragma unroll
  for (int a = 0; a < 4; ++a)
#pragma unroll
    for (int b = 0; b < 4; ++b) acc[a][b] = (f32x4){0.f, 0.f, 0.f, 0.f};
  const int ad = tid >> 2, an0 = (tid & 3) * 32;
  const int bc = tid >> 1, bd0 = (tid & 1) * 32;
  for (int kb = 0; kb < 640; kb += 64) {
    const float* ap = Wo + (size_t)(hh * 640 + kb + ad) * 5120 + n0 + an0;
#pragma unroll
    for (int i = 0; i < 32; ++i) As[(an0 + i) * 72 + ad] = f2bf(ap[i]);
    const float* bp = Wuv + (size_t)bc * 5120 + hh * 640 + kb + bd0;
    us8 bv0, bv1, bv2, bv3;
#pragma unroll
    for (int i = 0; i < 8; ++i) {
      bv0[i] = f2bf(bp[i]); bv1[i] = f2bf(bp[8 + i]);
      bv2[i] = f2bf(bp[16 + i]); bv3[i] = f2bf(bp[24 + i]);
    }
    *(us8*)&Bs[bc * 72 + bd0] = bv0;
    *(us8*)&Bs[bc * 72 + bd0 + 8] = bv1;
    *(us8*)&Bs[bc * 72 + bd0 + 16] = bv2;
    *(us8*)&Bs[bc * 72 + bd0 + 24] = bv3;
    __syncthreads();
#pragma unroll
    for (int ks = 0; ks < 2; ++ks) {
      short8 a[4], b[4];
#pragma unroll
      for (int mt = 0; mt < 4; ++mt)
        a[mt] = *(const short8*)&As[(wm * 64 + mt * 16 + l15) * 72 + ks * 32 + quad * 8];
#pragma unroll
      for (int nt = 0; nt < 4; ++nt)
        b[nt] = *(const short8*)&Bs[(wn * 64 + nt * 16 + l15) * 72 + ks * 32 + quad * 8];
#pragma unroll
      for (int mt = 0; mt < 4; ++mt)
#pragma unroll
        for (int nt = 0; nt < 4; ++nt) acc[mt][nt] = MFMA(a[mt], b[nt], acc[mt][nt]);
    }
    __syncthreads();
  }
#pragma unroll
  for (int mt = 0; mt < 4; ++mt)
#pragma unroll
    for (int nt = 0; nt < 4; ++nt) {
      int col = wn * 64 + nt * 16 + l15;
#pragma unroll
      for (int r = 0; r < 4; ++r) {
        int n = n0 + wm * 64 + mt * 16 + quad * 4 + r;
        wcombT[(size_t)n * 1024 + hh * 128 + col] = f2bf(acc[mt][nt][r]);
      }
    }
}

// ---------------------------------------------------------------------------
// Flash attention over absorbed dims. grid (32 q-tiles, 16 bh), block 256.
// Q/K 144-dim (pad->160), V = c_kv (128). ctx out bf16 (b,s,h,128).
__global__ __launch_bounds__(256) void k_attn(const ushort_t* __restrict__ qabs,
                                              const ushort_t* __restrict__ qrot,
                                              const ushort_t* __restrict__ ckv,
                                              const ushort_t* __restrict__ krot,
                                              ushort_t* __restrict__ ctx) {
  __shared__ __align__(16) ushort_t Qs[64 * 160];
  __shared__ __align__(16) ushort_t Ks[64 * 160];
  __shared__ __align__(16) ushort_t Vt[128 * 72];
  __shared__ __align__(16) ushort_t Ps[64 * 72];
  const int tid = threadIdx.x;
  const int bh = blockIdx.y, bb = bh >> 3, hh = bh & 7;
  const int q0 = blockIdx.x * 64;
  const int lane = tid & 63, wid = tid >> 6;
  const int quad = lane >> 4, l15 = lane & 15;
  const int sr = tid >> 2, sseg = tid & 3;
  {
    const ushort_t* qa = qabs + ((size_t)bh * 2048 + q0 + sr) * 128 + sseg * 32;
#pragma unroll
    for (int w = 0; w < 4; ++w)
      *(us8*)&Qs[sr * 160 + sseg * 32 + w * 8] = *(const us8*)(qa + w * 8);
    if (sseg == 0) {
      const ushort_t* qr = qrot + ((size_t)bh * 2048 + q0 + sr) * 16;
      *(us8*)&Qs[sr * 160 + 128] = *(const us8*)qr;
      *(us8*)&Qs[sr * 160 + 136] = *(const us8*)(qr + 8);
    }
    if (sseg == 1) {
      us8 z = (us8)0;
      *(us8*)&Qs[sr * 160 + 144] = z;
      *(us8*)&Qs[sr * 160 + 152] = z;
    }
  }
  f32x4 oacc[8];
#pragma unroll
  for (int i = 0; i < 8; ++i) oacc[i] = (f32x4){0.f, 0.f, 0.f, 0.f};
  float mrow[4] = {-1e30f, -1e30f, -1e30f, -1e30f};
  float lrow[4] = {0.f, 0.f, 0.f, 0.f};

  for (int kt = 0; kt < 32; ++kt) {
    int key0 = kt * 64;
    {
      const ushort_t* kp = ckv + ((size_t)bb * 2048 + key0 + sr) * 128 + sseg * 32;
      us8 v[4];
#pragma unroll
      for (int w = 0; w < 4; ++w) v[w] = *(const us8*)(kp + w * 8);
#pragma unroll
      for (int w = 0; w < 4; ++w)
        *(us8*)&Ks[sr * 160 + sseg * 32 + w * 8] = v[w];
#pragma unroll
      for (int w = 0; w < 4; ++w)
#pragma unroll
        for (int i = 0; i < 8; ++i)
          Vt[(sseg * 32 + w * 8 + i) * 72 + sr] = v[w][i];
      if (sseg == 0) {
        const ushort_t* kr = krot + ((size_t)bh * 2048 + key0 + sr) * 16;
        *(us8*)&Ks[sr * 160 + 128] = *(const us8*)kr;
        *(us8*)&Ks[sr * 160 + 136] = *(const us8*)(kr + 8);
      }
      if (sseg == 1) {
        us8 z = (us8)0;
        *(us8*)&Ks[sr * 160 + 144] = z;
        *(us8*)&Ks[sr * 160 + 152] = z;
      }
    }
    __syncthreads();
    // ---- QK^T (144 real + 16 zero dims)
    f32x4 sacc[4];
#pragma unroll
    for (int nt = 0; nt < 4; ++nt) sacc[nt] = (f32x4){0.f, 0.f, 0.f, 0.f};
#pragma unroll
    for (int ks = 0; ks < 5; ++ks) {
      short8 aq = *(const short8*)&Qs[(wid * 16 + l15) * 160 + ks * 32 + quad * 8];
#pragma unroll
      for (int nt = 0; nt < 4; ++nt) {
        short8 bk = *(const short8*)&Ks[(nt * 16 + l15) * 160 + ks * 32 + quad * 8];
        sacc[nt] = MFMA(aq, bk, sacc[nt]);
      }
    }
    // ---- online softmax (each wave owns complete score rows)
    float p[4][4];
#pragma unroll
    for (int r = 0; r < 4; ++r) {
      float mx = -1e30f;
#pragma unroll
      for (int nt = 0; nt < 4; ++nt) {
        sacc[nt][r] *= SCALE_ATT;
        mx = fmaxf(mx, sacc[nt][r]);
      }
#pragma unroll
      for (int off = 1; off < 16; off <<= 1) mx = fmaxf(mx, __shfl_xor(mx, off));
      float mnew = fmaxf(mrow[r], mx);
      float alpha = __expf(mrow[r] - mnew);
      mrow[r] = mnew;
      float rs = 0.f;
#pragma unroll
      for (int nt = 0; nt < 4; ++nt) {
        float pv = __expf(sacc[nt][r] - mnew);
        p[nt][r] = pv;
        rs += pv;
      }
#pragma unroll
      for (int off = 1; off < 16; off <<= 1) rs += __shfl_xor(rs, off);
      lrow[r] = lrow[r] * alpha + rs;
#pragma unroll
      for (int t8 = 0; t8 < 8; ++t8) oacc[t8][r] *= alpha;
    }
#pragma unroll
    for (int nt = 0; nt < 4; ++nt)
#pragma unroll
      for (int r = 0; r < 4; ++r)
        Ps[(wid * 16 + quad * 4 + r) * 72 + nt * 16 + l15] = f2bf(p[nt][r]);
    __syncthreads();
    // ---- PV: oacc += P(16x64) @ c_kv_tile(64x128)
#pragma unroll
    for (int kk = 0; kk < 2; ++kk) {
      short8 pa = *(const short8*)&Ps[(wid * 16 + l15) * 72 + kk * 32 + quad * 8];
#pragma unroll
      for (int nt = 0; nt < 8; ++nt) {
        short8 vb = *(const short8*)&Vt[(nt * 16 + l15) * 72 + kk * 32 + quad * 8];
        oacc[nt] = MFMA(pa, vb, oacc[nt]);
      }
    }
    __syncthreads();
  }
#pragma unroll
  for (int r = 0; r < 4; ++r) {
    float rl = 1.f / lrow[r];
    int row = q0 + wid * 16 + quad * 4 + r;
    size_t base = ((size_t)bb * 2048 + row) * 1024 + hh * 128;
#pragma unroll
    for (int nt = 0; nt < 8; ++nt)
      ctx[base + nt * 16 + l15] = f2bf(oacc[nt][r] * rl);
  }
}

// ---------------------------------------------------------------------------
// out = ctx(4096x1024) @ wcombT^T + bvec.  BM=BN=128, BK=64, K=1024. grid (32,40)
__global__ __launch_bounds__(256) void k_final(const ushort_t* __restrict__ ctx,
                                               const ushort_t* __restrict__ wcombT,
                                               const float* __restrict__ bvec,
                                               float* __restrict__ out) {
  __shared__ __align__(16) ushort_t As[128 * 72];
  __shared__ __align__(16) ushort_t Bs[128 * 72];
  const int tid = threadIdx.x;
  const int m0 = blockIdx.x * 128, n0 = blockIdx.y * 128;
  const int lane = tid & 63, wid = tid >> 6;
  const int quad = lane >> 4, l15 = lane & 15;
  const int wm = wid & 1, wn = wid >> 1;
  f32x4 acc[4][4];
#pragma unroll
  for (int a = 0; a < 4; ++a)
#pragma unroll
    for (int b = 0; b < 4; ++b) acc[a][b] = (f32x4){0.f, 0.f, 0.f, 0.f};
  const int ar = tid >> 1, as0 = (tid & 1) * 32;
  for (int kb = 0; kb < 1024; kb += 64) {
    const ushort_t* ap = ctx + (size_t)(m0 + ar) * 1024 + kb + as0;
    const ushort_t* bp = wcombT + (size_t)(n0 + ar) * 1024 + kb + as0;
#pragma unroll
    for (int w = 0; w < 4; ++w) {
      *(us8*)&As[ar * 72 + as0 + w * 8] = *(const us8*)(ap + w * 8);
      *(us8*)&Bs[ar * 72 + as0 + w * 8] = *(const us8*)(bp + w * 8);
    }
    __syncthreads();
#pragma unroll
    for (int ks = 0; ks < 2; ++ks) {
      short8 a[4], b[4];
#pragma unroll
      for (int mt = 0; mt < 4; ++mt)
        a[mt] = *(const short8*)&As[(wm * 64 + mt * 16 + l15) * 72 + ks * 32 + quad * 8];
#pragma unroll
      for (int nt = 0; nt < 4; ++nt)
        b[nt] = *(const short8*)&Bs[(wn * 64 + nt * 16 + l15) * 72 + ks * 32 + quad * 8];
#pragma unroll
      for (int mt = 0; mt < 4; ++mt)
#pragma unroll
        for (int nt = 0; nt < 4; ++nt) acc[mt][nt] = MFMA(a[mt], b[nt], acc[mt][nt]);
    }
    __syncthreads();
  }
#pragma unroll
  for (int mt = 0; mt < 4; ++mt)
#pragma unroll
    for (int nt = 0; nt < 4; ++nt) {
      int col = wn * 64 + nt * 16 + l15;
      float bias = bvec[n0 + col];
#pragma unroll
      for (int r = 0; r < 4; ++r) {
        int row = m0 + wm * 64 + mt * 16 + quad * 4 + r;
        out[(size_t)row * 5120 + n0 + col] = acc[mt][nt][r] + bias;
      }
    }
}

// ---------------------------------------------------------------------------
extern "C" void kernel_launch(void* const* d_in, const int* in_sizes, int n_in,
                              void* d_out, int out_size, void* d_ws, size_t ws_size,
                              hipStream_t stream) {
  const float* H    = (const float*)d_in[0];
  const float* Wdkv = (const float*)d_in[1];
  const float* bdkv = (const float*)d_in[2];
  const float* Wdq  = (const float*)d_in[3];
  const float* bdq  = (const float*)d_in[4];
  const float* Wuk  = (const float*)d_in[5];
  // d_in[6] = b_uk : softmax-invariant (constant per score row) -> unused
  const float* Wuv  = (const float*)d_in[7];
  const float* buv  = (const float*)d_in[8];
  const float* Wuq  = (const float*)d_in[9];
  const float* buq  = (const float*)d_in[10];
  const float* Wqr  = (const float*)d_in[11];
  const float* bqr  = (const float*)d_in[12];
  const float* Wkr  = (const float*)d_in[13];
  const float* bkr  = (const float*)d_in[14];
  const float* Wo   = (const float*)d_in[15];
  const float* bo   = (const float*)d_in[16];
  float* out = (float*)d_out;

  char* ws = (char*)d_ws;
  size_t off = 0;
  auto alloc = [&](size_t bytes) -> void* {
    void* p = ws + off;
    off += (bytes + 255) & ~(size_t)255;
    return p;
  };
  ushort_t* ckv    = (ushort_t*)alloc((size_t)4096 * 128 * 2);
  ushort_t* cq     = (ushort_t*)alloc((size_t)4096 * 128 * 2);
  ushort_t* krot   = (ushort_t*)alloc((size_t)16 * 2048 * 16 * 2);
  ushort_t* qrot   = (ushort_t*)alloc((size_t)16 * 2048 * 16 * 2);
  ushort_t* qabs   = (ushort_t*)alloc((size_t)16 * 2048 * 128 * 2);
  ushort_t* wqkT   = (ushort_t*)alloc((size_t)8 * 128 * 128 * 2);
  float*    bqabs  = (float*)alloc((size_t)8 * 128 * 4);
  ushort_t* wcombT = (ushort_t*)alloc((size_t)5120 * 1024 * 2);
  float*    bvec   = (float*)alloc((size_t)5120 * 4);
  ushort_t* ctx    = (ushort_t*)alloc((size_t)4096 * 1024 * 2);
  (void)ws_size; (void)in_sizes; (void)n_in; (void)out_size;

  hipLaunchKernelGGL(k_bvec_init, dim3(20), dim3(256), 0, stream, bo, bvec);
  hipLaunchKernelGGL(k_bvec_acc, dim3(5, 64), dim3(256), 0, stream, buv, Wo, bvec);
  hipLaunchKernelGGL(k_bqabs, dim3(8), dim3(128), 0, stream, buq, Wuk, bqabs);
  hipLaunchKernelGGL(k_wqk, dim3(8, 8, 8), dim3(256), 0, stream, Wuq, Wuk, wqkT);
  hipLaunchKernelGGL(k_gemm1, dim3(64, 3), dim3(256), 0, stream,
                     H, Wdkv, Wdq, Wkr, bdkv, bdq, bkr, ckv, cq, krot);
  hipLaunchKernelGGL(k_comb, dim3(40, 8), dim3(256), 0, stream, Wo, Wuv, wcombT);
  hipLaunchKernelGGL(k_qrot, dim3(128), dim3(256), 0, stream, cq, Wqr, bqr, qrot);
  hipLaunchKernelGGL(k_qabs, dim3(32, 8), dim3(256), 0, stream, cq, wqkT, bqabs, qabs);
  hipLaunchKernelGGL(k_attn, dim3(32, 16), dim3(256), 0, stream, qabs, qrot, ckv, krot, ctx);
  hipLaunchKernelGGL(k_final, dim3(32, 40), dim3(256), 0, stream, ctx, wcombT, bvec, out);
}

// Round 3
// 741.376 us; speedup vs baseline: 1.4754x; 1.1460x over previous
//
#include <hip/hip_runtime.h>

// ---------------------------------------------------------------------------
// MemoryOptimizedMLA on gfx950 — absorbed-MLA formulation.
//
//   c_kv = h@W_dkv+b ; c_q = h@W_dq+b ; k_rot = rope(h@W_kr+b)
//   W_qk[h] = W_uq_h @ W_uk_h^T (128x128), b_qabs[h] = b_uq_h @ W_uk_h^T
//   q_abs = c_q@W_qk + b_qabs ; q_rot = rope(c_q@W_qr + b_qr)
//   scores = (q_abs . c_kv + q_rot . k_rot)/sqrt(640)   (b_uk is softmax-inv.)
//   ctx = softmax(scores) @ c_kv      (128 dims, flash/online-softmax)
//   out = ctx @ W_combT^T + (b_uv@W_o + b_o),  W_comb[h] = W_uv_h @ W_o_h
//
// R2: gemm1 rebuilt as split-K (grid 64x2x4, fp32 partials) + k_reduce
//     epilogue (bias + rope). part ws aliases qabs/wcombT/ctx (stream-ordered).
// ---------------------------------------------------------------------------

typedef unsigned short ushort_t;
typedef __attribute__((ext_vector_type(8)))  short          short8;
typedef __attribute__((ext_vector_type(8)))  unsigned short us8;
typedef __attribute__((ext_vector_type(4)))  float          f32x4;

#define SCALE_ATT 0.0395284707521047f  /* 1/sqrt(640) */

static __device__ inline unsigned short f2bf(float f) {
  union { float f; unsigned u; } v; v.f = f;
  unsigned r = (v.u + 0x7fffu + ((v.u >> 16) & 1u)) >> 16;
  return (unsigned short)r;
}
static __device__ inline float bf2f(unsigned short u) {
  union { unsigned u; float f; } v; v.u = ((unsigned)u) << 16;
  return v.f;
}
static __device__ inline f32x4 MFMA(short8 a, short8 b, f32x4 c) {
  return __builtin_amdgcn_mfma_f32_16x16x32_bf16(a, b, c, 0, 0, 0);
}

// ---------------------------------------------------------------------------
// bvec init: bvec[n] = bo[n].  grid 20, block 256.
__global__ __launch_bounds__(256) void k_bvec_init(const float* __restrict__ bo,
                                                   float* __restrict__ bvec) {
  int n = blockIdx.x * 256 + threadIdx.x;
  bvec[n] = bo[n];
}

// bvec accumulate: bvec[n] += sum_k buv[k]*Wo[k][n].
__global__ __launch_bounds__(256) void k_bvec_acc(const float* __restrict__ buv,
                                                  const float* __restrict__ Wo,
                                                  float* __restrict__ bvec) {
  const int n0 = blockIdx.x * 1024 + threadIdx.x * 4;
  const int k0 = blockIdx.y * 80;
  f32x4 acc = (f32x4){0.f, 0.f, 0.f, 0.f};
  const float* wp = Wo + (size_t)k0 * 5120 + n0;
#pragma unroll 4
  for (int k = 0; k < 80; ++k) {
    float bv = buv[k0 + k];
    const f32x4 w = *(const f32x4*)wp;
    acc[0] += bv * w[0]; acc[1] += bv * w[1];
    acc[2] += bv * w[2]; acc[3] += bv * w[3];
    wp += 5120;
  }
  atomicAdd(&bvec[n0 + 0], acc[0]);
  atomicAdd(&bvec[n0 + 1], acc[1]);
  atomicAdd(&bvec[n0 + 2], acc[2]);
  atomicAdd(&bvec[n0 + 3], acc[3]);
}

// ---------------------------------------------------------------------------
// bqabs[h][j] = sum_d b_uq[h*624+d] * W_uk[j][h*624+d]   grid 8, block 128
__global__ __launch_bounds__(128) void k_bqabs(const float* __restrict__ buq,
                                               const float* __restrict__ Wuk,
                                               float* __restrict__ bqabs) {
  int h = blockIdx.x, j = threadIdx.x;
  float acc = 0.f;
  const float* bq = buq + h * 624;
  const float* wk = Wuk + (size_t)j * 4992 + h * 624;
  for (int d = 0; d < 624; ++d) acc += bq[d] * wk[d];
  bqabs[h * 128 + j] = acc;
}

// ---------------------------------------------------------------------------
// wqkT[h][j][i] = sum_d W_uq[i][h*624+d]*W_uk[j][h*624+d]  (fp32, then bf16)
__global__ __launch_bounds__(256) void k_wqk(const float* __restrict__ Wuq,
                                             const float* __restrict__ Wuk,
                                             ushort_t* __restrict__ wqkT) {
  __shared__ float Aq[16 * 132];
  __shared__ float Ak[16 * 132];
  int jt = blockIdx.x, it = blockIdx.y, h = blockIdx.z;
  int i0 = it * 16, j0 = jt * 16;
  int t = threadIdx.x;
  int srow = t >> 4, sc0 = (t & 15) * 8;
  int ti = t & 15, tj = t >> 4;
  float acc = 0.f;
  for (int dc = 0; dc < 624; dc += 128) {
#pragma unroll
    for (int i = 0; i < 8; ++i) {
      int d = dc + sc0 + i;
      Aq[srow * 132 + sc0 + i] = (d < 624) ? Wuq[(size_t)(i0 + srow) * 4992 + h * 624 + d] : 0.f;
      Ak[srow * 132 + sc0 + i] = (d < 624) ? Wuk[(size_t)(j0 + srow) * 4992 + h * 624 + d] : 0.f;
    }
    __syncthreads();
    int cs = (624 - dc) < 128 ? (624 - dc) : 128;
    for (int d = 0; d < cs; d += 4) {
      const f32x4 a4 = *(const f32x4*)&Aq[ti * 132 + d];
      const f32x4 b4 = *(const f32x4*)&Ak[tj * 132 + d];
      acc += a4[0] * b4[0] + a4[1] * b4[1] + a4[2] * b4[2] + a4[3] * b4[3];
    }
    __syncthreads();
  }
  wqkT[(size_t)h * 16384 + (size_t)(j0 + tj) * 128 + (i0 + ti)] = f2bf(acc);
}

// ---------------------------------------------------------------------------
// GEMM1 split-K: partials of h @ [W_dkv|W_dq|W_kr].
// grid (64 mtiles, 2 nhalves, 4 ksplits), block 256 (4 waves, each 64x48).
// BM=64, BN=192, BK=64, KC=1280. fp32 partials -> part[ks][4096][384].
__global__ __launch_bounds__(256) void k_gemm1_sk(
    const float* __restrict__ H, const float* __restrict__ Wdkv,
    const float* __restrict__ Wdq, const float* __restrict__ Wkr,
    float* __restrict__ part) {
  __shared__ __align__(16) ushort_t As[64 * 72];
  __shared__ __align__(16) ushort_t Bs[192 * 72];
  const int tid = threadIdx.x;
  const int m0 = blockIdx.x * 64;
  const int n0 = blockIdx.y * 192;
  const int kc0 = blockIdx.z * 1280;
  const int lane = tid & 63, wid = tid >> 6;
  const int quad = lane >> 4, l15 = lane & 15;
  f32x4 acc[4][3];
#pragma unroll
  for (int a = 0; a < 4; ++a)
#pragma unroll
    for (int b = 0; b < 3; ++b) acc[a][b] = (f32x4){0.f, 0.f, 0.f, 0.f};
  const int ar = tid >> 2, ak0 = (tid & 3) * 16;
  const int br = tid >> 2, bc0 = (tid & 3) * 48;
  const float* harow = H + (size_t)(m0 + ar) * 5120 + ak0;
  for (int kb = kc0; kb < kc0 + 1280; kb += 64) {
    const float* ap = harow + kb;
    us8 av0, av1;
#pragma unroll
    for (int i = 0; i < 8; ++i) { av0[i] = f2bf(ap[i]); av1[i] = f2bf(ap[8 + i]); }
    *(us8*)&As[ar * 72 + ak0] = av0;
    *(us8*)&As[ar * 72 + ak0 + 8] = av1;
#pragma unroll
    for (int g16 = 0; g16 < 3; ++g16) {
      const int lcol = bc0 + g16 * 16;
      const int col = n0 + lcol;
      const float* base = (col < 128 ? Wdkv + col
                         : col < 256 ? Wdq + (col - 128)
                                     : Wkr + (col - 256)) + (size_t)(kb + br) * 128;
#pragma unroll
      for (int i = 0; i < 16; ++i)
        Bs[(lcol + i) * 72 + br] = f2bf(base[i]);
    }
    __syncthreads();
#pragma unroll
    for (int ks = 0; ks < 2; ++ks) {
      short8 a[4], b[3];
#pragma unroll
      for (int mt = 0; mt < 4; ++mt)
        a[mt] = *(const short8*)&As[(mt * 16 + l15) * 72 + ks * 32 + quad * 8];
#pragma unroll
      for (int nt = 0; nt < 3; ++nt)
        b[nt] = *(const short8*)&Bs[(wid * 48 + nt * 16 + l15) * 72 + ks * 32 + quad * 8];
#pragma unroll
      for (int mt = 0; mt < 4; ++mt)
#pragma unroll
        for (int nt = 0; nt < 3; ++nt) acc[mt][nt] = MFMA(a[mt], b[nt], acc[mt][nt]);
    }
    __syncthreads();
  }
  const size_t pb = (size_t)blockIdx.z * 4096 * 384;
#pragma unroll
  for (int mt = 0; mt < 4; ++mt)
#pragma unroll
    for (int nt = 0; nt < 3; ++nt) {
      const int col = n0 + wid * 48 + nt * 16 + l15;
#pragma unroll
      for (int r = 0; r < 4; ++r) {
        const int row = m0 + mt * 16 + quad * 4 + r;
        part[pb + (size_t)row * 384 + col] = acc[mt][nt][r];
      }
    }
}

// ---------------------------------------------------------------------------
// reduce 4 partials + bias; rope for the k_rot slice. grid 4096, block 384.
__global__ __launch_bounds__(384) void k_reduce(
    const float* __restrict__ part, const float* __restrict__ bdkv,
    const float* __restrict__ bdq, const float* __restrict__ bkr,
    ushort_t* __restrict__ ckv, ushort_t* __restrict__ cq,
    ushort_t* __restrict__ krot) {
  const int row = blockIdx.x;
  const int c = threadIdx.x;
  float v = 0.f;
#pragma unroll
  for (int ks = 0; ks < 4; ++ks)
    v += part[((size_t)ks * 4096 + row) * 384 + c];
  if (c < 128) {
    v += bdkv[c];
    ckv[(size_t)row * 128 + c] = f2bf(v);
  } else if (c < 256) {
    v += bdq[c - 128];
    cq[(size_t)row * 128 + (c - 128)] = f2bf(v);
  } else {
    v += bkr[c - 256];
    float partner = __shfl_xor(v, 4);
    const int j = (c - 256) & 15;
    const int head = (c - 256) >> 4;
    const int s = row & 2047, bb = row >> 11;
    const int j4 = j & 3;
    const float fr = (j4 == 0) ? 1.f : (j4 == 1) ? 0.1f : (j4 == 2) ? 0.01f : 0.001f;
    float sth, cth;
    __sincosf(s * 0.025f * fr, &sth, &cth);
    const float y = (j < 4) ? (v * cth - partner * sth)
                  : (j < 8) ? (v * cth + partner * sth) : v;
    krot[((size_t)((bb << 3) + head) * 2048 + s) * 16 + j] = f2bf(y);
  }
}

// ---------------------------------------------------------------------------
// q_rot = rope(c_q @ W_qr + b_qr).  one thread per (b,h,s).  grid 128, block 256.
__global__ __launch_bounds__(256) void k_qrot(const ushort_t* __restrict__ cq,
                                              const float* __restrict__ Wqr,
                                              const float* __restrict__ bqr,
                                              ushort_t* __restrict__ qrot) {
  int gidx = blockIdx.x * 256 + threadIdx.x;  // 0..32767
  int s = gidx & 2047, bh = gidx >> 11;
  int hh = bh & 7, bb = bh >> 3;
  const ushort_t* crow = cq + ((size_t)bb * 2048 + s) * 128;
  float acc[16];
#pragma unroll
  for (int j = 0; j < 16; ++j) acc[j] = bqr[hh * 16 + j];
  for (int k0 = 0; k0 < 128; k0 += 8) {
    us8 cv8 = *(const us8*)(crow + k0);
#pragma unroll
    for (int i = 0; i < 8; ++i) {
      float cv = bf2f(cv8[i]);
      const float* wr = Wqr + (size_t)(k0 + i) * 128 + hh * 16;
#pragma unroll
      for (int j = 0; j < 16; ++j) acc[j] += cv * wr[j];
    }
  }
  float y[16];
#pragma unroll
  for (int j4 = 0; j4 < 4; ++j4) {
    float fr = (j4 == 0) ? 1.f : (j4 == 1) ? 0.1f : (j4 == 2) ? 0.01f : 0.001f;
    float sth, cth;
    __sincosf(s * 0.025f * fr, &sth, &cth);
    y[j4] = acc[j4] * cth - acc[j4 + 4] * sth;
    y[j4 + 4] = acc[j4 + 4] * cth + acc[j4] * sth;
  }
#pragma unroll
  for (int j = 8; j < 16; ++j) y[j] = acc[j];
  us8 o0, o1;
#pragma unroll
  for (int j = 0; j < 8; ++j) { o0[j] = f2bf(y[j]); o1[j] = f2bf(y[8 + j]); }
  *(us8*)(qrot + (size_t)gidx * 16) = o0;
  *(us8*)(qrot + (size_t)gidx * 16 + 8) = o1;
}

// ---------------------------------------------------------------------------
// q_abs = c_q @ W_qk[h] + b_qabs[h].  BM=128,BN=128,BK=64. grid (32, 8).
__global__ __launch_bounds__(256) void k_qabs(const ushort_t* __restrict__ cq,
                                              const ushort_t* __restrict__ wqkT,
                                              const float* __restrict__ bqabs,
                                              ushort_t* __restrict__ qabs) {
  __shared__ __align__(16) ushort_t As[128 * 72];
  __shared__ __align__(16) ushort_t Bs[128 * 72];
  const int tid = threadIdx.x;
  const int m0 = blockIdx.x * 128, hh = blockIdx.y;
  const int lane = tid & 63, wid = tid >> 6;
  const int quad = lane >> 4, l15 = lane & 15;
  const int wm = wid & 1, wn = wid >> 1;
  f32x4 acc[4][4];
#pragma unroll
  for (int a = 0; a < 4; ++a)
#pragma unroll
    for (int b = 0; b < 4; ++b) acc[a][b] = (f32x4){0.f, 0.f, 0.f, 0.f};
  const int ar = tid >> 1, as0 = (tid & 1) * 32;
  for (int kb = 0; kb < 128; kb += 64) {
    const ushort_t* ap = cq + (size_t)(m0 + ar) * 128 + kb + as0;
    const ushort_t* bp = wqkT + (size_t)hh * 16384 + (size_t)ar * 128 + kb + as0;
#pragma unroll
    for (int w = 0; w < 4; ++w) {
      *(us8*)&As[ar * 72 + as0 + w * 8] = *(const us8*)(ap + w * 8);
      *(us8*)&Bs[ar * 72 + as0 + w * 8] = *(const us8*)(bp + w * 8);
    }
    __syncthreads();
#pragma unroll
    for (int ks = 0; ks < 2; ++ks) {
      short8 a[4], b[4];
#pragma unroll
      for (int mt = 0; mt < 4; ++mt)
        a[mt] = *(const short8*)&As[(wm * 64 + mt * 16 + l15) * 72 + ks * 32 + quad * 8];
#pragma unroll
      for (int nt = 0; nt < 4; ++nt)
        b[nt] = *(const short8*)&Bs[(wn * 64 + nt * 16 + l15) * 72 + ks * 32 + quad * 8];
#pragma unroll
      for (int mt = 0; mt < 4; ++mt)
#pragma unroll
        for (int nt = 0; nt < 4; ++nt) acc[mt][nt] = MFMA(a[mt], b[nt], acc[mt][nt]);
    }
    __syncthreads();
  }
#pragma unroll
  for (int mt = 0; mt < 4; ++mt)
#pragma unroll
    for (int nt = 0; nt < 4; ++nt) {
      int col = wn * 64 + nt * 16 + l15;
      float bias = bqabs[hh * 128 + col];
#pragma unroll
      for (int r = 0; r < 4; ++r) {
        int m = m0 + wm * 64 + mt * 16 + quad * 4 + r;
        int bb = m >> 11, s = m & 2047;
        qabs[((size_t)((bb << 3) + hh) * 2048 + s) * 128 + col] = f2bf(acc[mt][nt][r] + bias);
      }
    }
}

// ---------------------------------------------------------------------------
// wcombT[n][h*128+c] = sum_d W_o[h*640+d][n] * W_uv[c][h*640+d]
__global__ __launch_bounds__(256) void k_comb(const float* __restrict__ Wo,
                                              const float* __restrict__ Wuv,
                                              ushort_t* __restrict__ wcombT) {
  __shared__ __align__(16) ushort_t As[128 * 72];
  __shared__ __align__(16) ushort_t Bs[128 * 72];
  const int tid = threadIdx.x;
  const int n0 = blockIdx.x * 128, hh = blockIdx.y;
  const int lane = tid & 63, wid = tid >> 6;
  const int quad = lane >> 4, l15 = lane & 15;
  const int wm = wid & 1, wn = wid >> 1;
  f32x4 acc[4][4];
#pragma unroll
  for (int a = 0; a < 4; ++a)
#pragma unroll
    for (int b = 0; b < 4; ++b) acc[a][b] = (f32x4){0.f, 0.f, 0.f, 0.f};
  const int ad = tid >> 2, an0 = (tid & 3) * 32;
  const int bc = tid >> 1, bd0 = (tid & 1) * 32;
  for (int kb = 0; kb < 640; kb += 64) {
    const float* ap = Wo + (size_t)(hh * 640 + kb + ad) * 5120 + n0 + an0;
#pragma unroll
    for (int i = 0; i < 32; ++i) As[(an0 + i) * 72 + ad] = f2bf(ap[i]);
    const float* bp = Wuv + (size_t)bc * 5120 + hh * 640 + kb + bd0;
    us8 bv0, bv1, bv2, bv3;
#pragma unroll
    for (int i = 0; i < 8; ++i) {
      bv0[i] = f2bf(bp[i]); bv1[i] = f2bf(bp[8 + i]);
      bv2[i] = f2bf(bp[16 + i]); bv3[i] = f2bf(bp[24 + i]);
    }
    *(us8*)&Bs[bc * 72 + bd0] = bv0;
    *(us8*)&Bs[bc * 72 + bd0 + 8] = bv1;
    *(us8*)&Bs[bc * 72 + bd0 + 16] = bv2;
    *(us8*)&Bs[bc * 72 + bd0 + 24] = bv3;
    __syncthreads();
#pragma unroll
    for (int ks = 0; ks < 2; ++ks) {
      short8 a[4], b[4];
#pragma unroll
      for (int mt = 0; mt < 4; ++mt)
        a[mt] = *(const short8*)&As[(wm * 64 + mt * 16 + l15) * 72 + ks * 32 + quad * 8];
#pragma unroll
      for (int nt = 0; nt < 4; ++nt)
        b[nt] = *(const short8*)&Bs[(wn * 64 + nt * 16 + l15) * 72 + ks * 32 + quad * 8];
#pragma unroll
      for (int mt = 0; mt < 4; ++mt)
#pragma unroll
        for (int nt = 0; nt < 4; ++nt) acc[mt][nt] = MFMA(a[mt], b[nt], acc[mt][nt]);
    }
    __syncthreads();
  }
#pragma unroll
  for (int mt = 0; mt < 4; ++mt)
#pragma unroll
    for (int nt = 0; nt < 4; ++nt) {
      int col = wn * 64 + nt * 16 + l15;
#pragma unroll
      for (int r = 0; r < 4; ++r) {
        int n = n0 + wm * 64 + mt * 16 + quad * 4 + r;
        wcombT[(size_t)n * 1024 + hh * 128 + col] = f2bf(acc[mt][nt][r]);
      }
    }
}

// ---------------------------------------------------------------------------
// Flash attention over absorbed dims. grid (32 q-tiles, 16 bh), block 256.
__global__ __launch_bounds__(256) void k_attn(const ushort_t* __restrict__ qabs,
                                              const ushort_t* __restrict__ qrot,
                                              const ushort_t* __restrict__ ckv,
                                              const ushort_t* __restrict__ krot,
                                              ushort_t* __restrict__ ctx) {
  __shared__ __align__(16) ushort_t Qs[64 * 160];
  __shared__ __align__(16) ushort_t Ks[64 * 160];
  __shared__ __align__(16) ushort_t Vt[128 * 72];
  __shared__ __align__(16) ushort_t Ps[64 * 72];
  const int tid = threadIdx.x;
  const int bh = blockIdx.y, bb = bh >> 3, hh = bh & 7;
  const int q0 = blockIdx.x * 64;
  const int lane = tid & 63, wid = tid >> 6;
  const int quad = lane >> 4, l15 = lane & 15;
  const int sr = tid >> 2, sseg = tid & 3;
  {
    const ushort_t* qa = qabs + ((size_t)bh * 2048 + q0 + sr) * 128 + sseg * 32;
#pragma unroll
    for (int w = 0; w < 4; ++w)
      *(us8*)&Qs[sr * 160 + sseg * 32 + w * 8] = *(const us8*)(qa + w * 8);
    if (sseg == 0) {
      const ushort_t* qr = qrot + ((size_t)bh * 2048 + q0 + sr) * 16;
      *(us8*)&Qs[sr * 160 + 128] = *(const us8*)qr;
      *(us8*)&Qs[sr * 160 + 136] = *(const us8*)(qr + 8);
    }
    if (sseg == 1) {
      us8 z = (us8)0;
      *(us8*)&Qs[sr * 160 + 144] = z;
      *(us8*)&Qs[sr * 160 + 152] = z;
    }
  }
  f32x4 oacc[8];
#pragma unroll
  for (int i = 0; i < 8; ++i) oacc[i] = (f32x4){0.f, 0.f, 0.f, 0.f};
  float mrow[4] = {-1e30f, -1e30f, -1e30f, -1e30f};
  float lrow[4] = {0.f, 0.f, 0.f, 0.f};

  for (int kt = 0; kt < 32; ++kt) {
    int key0 = kt * 64;
    {
      const ushort_t* kp = ckv + ((size_t)bb * 2048 + key0 + sr) * 128 + sseg * 32;
      us8 v[4];
#pragma unroll
      for (int w = 0; w < 4; ++w) v[w] = *(const us8*)(kp + w * 8);
#pragma unroll
      for (int w = 0; w < 4; ++w)
        *(us8*)&Ks[sr * 160 + sseg * 32 + w * 8] = v[w];
#pragma unroll
      for (int w = 0; w < 4; ++w)
#pragma unroll
        for (int i = 0; i < 8; ++i)
          Vt[(sseg * 32 + w * 8 + i) * 72 + sr] = v[w][i];
      if (sseg == 0) {
        const ushort_t* kr = krot + ((size_t)bh * 2048 + key0 + sr) * 16;
        *(us8*)&Ks[sr * 160 + 128] = *(const us8*)kr;
        *(us8*)&Ks[sr * 160 + 136] = *(const us8*)(kr + 8);
      }
      if (sseg == 1) {
        us8 z = (us8)0;
        *(us8*)&Ks[sr * 160 + 144] = z;
        *(us8*)&Ks[sr * 160 + 152] = z;
      }
    }
    __syncthreads();
    f32x4 sacc[4];
#pragma unroll
    for (int nt = 0; nt < 4; ++nt) sacc[nt] = (f32x4){0.f, 0.f, 0.f, 0.f};
#pragma unroll
    for (int ks = 0; ks < 5; ++ks) {
      short8 aq = *(const short8*)&Qs[(wid * 16 + l15) * 160 + ks * 32 + quad * 8];
#pragma unroll
      for (int nt = 0; nt < 4; ++nt) {
        short8 bk = *(const short8*)&Ks[(nt * 16 + l15) * 160 + ks * 32 + quad * 8];
        sacc[nt] = MFMA(aq, bk, sacc[nt]);
      }
    }
    float p[4][4];
#pragma unroll
    for (int r = 0; r < 4; ++r) {
      float mx = -1e30f;
#pragma unroll
      for (int nt = 0; nt < 4; ++nt) {
        sacc[nt][r] *= SCALE_ATT;
        mx = fmaxf(mx, sacc[nt][r]);
      }
#pragma unroll
      for (int off = 1; off < 16; off <<= 1) mx = fmaxf(mx, __shfl_xor(mx, off));
      float mnew = fmaxf(mrow[r], mx);
      float alpha = __expf(mrow[r] - mnew);
      mrow[r] = mnew;
      float rs = 0.f;
#pragma unroll
      for (int nt = 0; nt < 4; ++nt) {
        float pv = __expf(sacc[nt][r] - mnew);
        p[nt][r] = pv;
        rs += pv;
      }
#pragma unroll
      for (int off = 1; off < 16; off <<= 1) rs += __shfl_xor(rs, off);
      lrow[r] = lrow[r] * alpha + rs;
#pragma unroll
      for (int t8 = 0; t8 < 8; ++t8) oacc[t8][r] *= alpha;
    }
#pragma unroll
    for (int nt = 0; nt < 4; ++nt)
#pragma unroll
      for (int r = 0; r < 4; ++r)
        Ps[(wid * 16 + quad * 4 + r) * 72 + nt * 16 + l15] = f2bf(p[nt][r]);
    __syncthreads();
#pragma unroll
    for (int kk = 0; kk < 2; ++kk) {
      short8 pa = *(const short8*)&Ps[(wid * 16 + l15) * 72 + kk * 32 + quad * 8];
#pragma unroll
      for (int nt = 0; nt < 8; ++nt) {
        short8 vb = *(const short8*)&Vt[(nt * 16 + l15) * 72 + kk * 32 + quad * 8];
        oacc[nt] = MFMA(pa, vb, oacc[nt]);
      }
    }
    __syncthreads();
  }
#pragma unroll
  for (int r = 0; r < 4; ++r) {
    float rl = 1.f / lrow[r];
    int row = q0 + wid * 16 + quad * 4 + r;
    size_t base = ((size_t)bb * 2048 + row) * 1024 + hh * 128;
#pragma unroll
    for (int nt = 0; nt < 8; ++nt)
      ctx[base + nt * 16 + l15] = f2bf(oacc[nt][r] * rl);
  }
}

// ---------------------------------------------------------------------------
// out = ctx(4096x1024) @ wcombT^T + bvec.  BM=BN=128, BK=64, K=1024. grid (32,40)
__global__ __launch_bounds__(256) void k_final(const ushort_t* __restrict__ ctx,
                                               const ushort_t* __restrict__ wcombT,
                                               const float* __restrict__ bvec,
                                               float* __restrict__ out) {
  __shared__ __align__(16) ushort_t As[128 * 72];
  __shared__ __align__(16) ushort_t Bs[128 * 72];
  const int tid = threadIdx.x;
  const int m0 = blockIdx.x * 128, n0 = blockIdx.y * 128;
  const int lane = tid & 63, wid = tid >> 6;
  const int quad = lane >> 4, l15 = lane & 15;
  const int wm = wid & 1, wn = wid >> 1;
  f32x4 acc[4][4];
#pragma unroll
  for (int a = 0; a < 4; ++a)
#pragma unroll
    for (int b = 0; b < 4; ++b) acc[a][b] = (f32x4){0.f, 0.f, 0.f, 0.f};
  const int ar = tid >> 1, as0 = (tid & 1) * 32;
  for (int kb = 0; kb < 1024; kb += 64) {
    const ushort_t* ap = ctx + (size_t)(m0 + ar) * 1024 + kb + as0;
    const ushort_t* bp = wcombT + (size_t)(n0 + ar) * 1024 + kb + as0;
#pragma unroll
    for (int w = 0; w < 4; ++w) {
      *(us8*)&As[ar * 72 + as0 + w * 8] = *(const us8*)(ap + w * 8);
      *(us8*)&Bs[ar * 72 + as0 + w * 8] = *(const us8*)(bp + w * 8);
    }
    __syncthreads();
#pragma unroll
    for (int ks = 0; ks < 2; ++ks) {
      short8 a[4], b[4];
#pragma unroll
      for (int mt = 0; mt < 4; ++mt)
        a[mt] = *(const short8*)&As[(wm * 64 + mt * 16 + l15) * 72 + ks * 32 + quad * 8];
#pragma unroll
      for (int nt = 0; nt < 4; ++nt)
        b[nt] = *(const short8*)&Bs[(wn * 64 + nt * 16 + l15) * 72 + ks * 32 + quad * 8];
#pragma unroll
      for (int mt = 0; mt < 4; ++mt)
#pragma unroll
        for (int nt = 0; nt < 4; ++nt) acc[mt][nt] = MFMA(a[mt], b[nt], acc[mt][nt]);
    }
    __syncthreads();
  }
#pragma unroll
  for (int mt = 0; mt < 4; ++mt)
#pragma unroll
    for (int nt = 0; nt < 4; ++nt) {
      int col = wn * 64 + nt * 16 + l15;
      float bias = bvec[n0 + col];
#pragma unroll
      for (int r = 0; r < 4; ++r) {
        int row = m0 + wm * 64 + mt * 16 + quad * 4 + r;
        out[(size_t)row * 5120 + n0 + col] = acc[mt][nt][r] + bias;
      }
    }
}

// ---------------------------------------------------------------------------
extern "C" void kernel_launch(void* const* d_in, const int* in_sizes, int n_in,
                              void* d_out, int out_size, void* d_ws, size_t ws_size,
                              hipStream_t stream) {
  const float* H    = (const float*)d_in[0];
  const float* Wdkv = (const float*)d_in[1];
  const float* bdkv = (const float*)d_in[2];
  const float* Wdq  = (const float*)d_in[3];
  const float* bdq  = (const float*)d_in[4];
  const float* Wuk  = (const float*)d_in[5];
  // d_in[6] = b_uk : softmax-invariant -> unused
  const float* Wuv  = (const float*)d_in[7];
  const float* buv  = (const float*)d_in[8];
  const float* Wuq  = (const float*)d_in[9];
  const float* buq  = (const float*)d_in[10];
  const float* Wqr  = (const float*)d_in[11];
  const float* bqr  = (const float*)d_in[12];
  const float* Wkr  = (const float*)d_in[13];
  const float* bkr  = (const float*)d_in[14];
  const float* Wo   = (const float*)d_in[15];
  const float* bo   = (const float*)d_in[16];
  float* out = (float*)d_out;

  char* ws = (char*)d_ws;
  size_t off = 0;
  auto alloc = [&](size_t bytes) -> void* {
    void* p = ws + off;
    off += (bytes + 255) & ~(size_t)255;
    return p;
  };
  // --- region A (persistent) ~4.5 MB
  ushort_t* ckv    = (ushort_t*)alloc((size_t)4096 * 128 * 2);
  ushort_t* cq     = (ushort_t*)alloc((size_t)4096 * 128 * 2);
  ushort_t* krot   = (ushort_t*)alloc((size_t)16 * 2048 * 16 * 2);
  ushort_t* qrot   = (ushort_t*)alloc((size_t)16 * 2048 * 16 * 2);
  ushort_t* wqkT   = (ushort_t*)alloc((size_t)8 * 128 * 128 * 2);
  float*    bqabs  = (float*)alloc((size_t)8 * 128 * 4);
  float*    bvec   = (float*)alloc((size_t)5120 * 4);
  // --- region B: split-K partials (25.2 MB), lifetime: gemm1_sk -> reduce
  size_t mark = off;
  float*    part   = (float*)alloc((size_t)4 * 4096 * 384 * 4);
  size_t endB = off;
  // --- region C aliases B (stream-ordered: all uses launch after k_reduce)
  off = mark;
  ushort_t* qabs   = (ushort_t*)alloc((size_t)16 * 2048 * 128 * 2);
  ushort_t* wcombT = (ushort_t*)alloc((size_t)5120 * 1024 * 2);
  ushort_t* ctx    = (ushort_t*)alloc((size_t)4096 * 1024 * 2);
  if (off < endB) off = endB;
  (void)ws_size; (void)in_sizes; (void)n_in; (void)out_size;

  hipLaunchKernelGGL(k_bvec_init, dim3(20), dim3(256), 0, stream, bo, bvec);
  hipLaunchKernelGGL(k_bvec_acc, dim3(5, 64), dim3(256), 0, stream, buv, Wo, bvec);
  hipLaunchKernelGGL(k_bqabs, dim3(8), dim3(128), 0, stream, buq, Wuk, bqabs);
  hipLaunchKernelGGL(k_wqk, dim3(8, 8, 8), dim3(256), 0, stream, Wuq, Wuk, wqkT);
  hipLaunchKernelGGL(k_gemm1_sk, dim3(64, 2, 4), dim3(256), 0, stream,
                     H, Wdkv, Wdq, Wkr, part);
  hipLaunchKernelGGL(k_reduce, dim3(4096), dim3(384), 0, stream,
                     part, bdkv, bdq, bkr, ckv, cq, krot);
  hipLaunchKernelGGL(k_comb, dim3(40, 8), dim3(256), 0, stream, Wo, Wuv, wcombT);
  hipLaunchKernelGGL(k_qrot, dim3(128), dim3(256), 0, stream, cq, Wqr, bqr, qrot);
  hipLaunchKernelGGL(k_qabs, dim3(32, 8), dim3(256), 0, stream, cq, wqkT, bqabs, qabs);
  hipLaunchKernelGGL(k_attn, dim3(32, 16), dim3(256), 0, stream, qabs, qrot, ckv, krot, ctx);
  hipLaunchKernelGGL(k_final, dim3(32, 40), dim3(256), 0, stream, ctx, wcombT, bvec, out);
}